// Round 2
// baseline (115.350 us; speedup 1.0000x reference)
//
#include <hip/hip_runtime.h>

typedef unsigned short u16;
typedef unsigned int u32;
typedef __bf16 b16x8 __attribute__((ext_vector_type(8)));
typedef float f32x16 __attribute__((ext_vector_type(16)));

#define SEQ   16384
#define DM    2048
#define KT    50
#define NST   48
#define NSP   49

// involution: swap rows 4-7 <-> 8-11 within each 16-block
__device__ __forceinline__ int perm64(int g){
  int q = (g>>2)&3;
  return (q==1 || q==2) ? (g^12) : g;
}
__device__ __forceinline__ u16 bfb(float f){
  __bf16 b = (__bf16)f;
  return __builtin_bit_cast(u16, b);
}
__device__ __forceinline__ int pk2(float a, float b){
  return (int)((u32)bfb(a) | ((u32)bfb(b) << 16));
}
__device__ __forceinline__ b16x8 cast8(int4 v){ return __builtin_bit_cast(b16x8, v); }

__device__ __forceinline__ f32x16 mfma_(b16x8 a, b16x8 b, f32x16 c){
  return __builtin_amdgcn_mfma_f32_32x32x16_bf16(a, b, c, 0, 0, 0);
}

// acc = A * B   (64x64x64, A-frags [mi][kt], B-frags [kt][ni])
__device__ __forceinline__ void mm64(const b16x8 A[2][4], const b16x8 B[4][2], f32x16 acc[2][2]){
#pragma unroll
  for (int mi=0; mi<2; ++mi)
#pragma unroll
    for (int ni=0; ni<2; ++ni){
      f32x16 a;
#pragma unroll
      for (int q=0;q<16;q++) a[q] = 0.0f;
#pragma unroll
      for (int kt=0; kt<4; ++kt) a = mfma_(A[mi][kt], B[kt][ni], a);
      acc[mi][ni] = a;
    }
}

// acc (C/D layout) -> B-frags of the next matmul (B_phys = Pi * ACC, in-lane).
__device__ __forceinline__ void repack(const f32x16 acc[2][2], b16x8 B[4][2]){
#pragma unroll
  for (int kb=0; kb<4; ++kb){
    const int mi = kb>>1, t = kb&1;
#pragma unroll
    for (int ni=0; ni<2; ++ni){
      int4 dw;
      dw.x = pk2(acc[mi][ni][8*t+0], acc[mi][ni][8*t+1]);
      dw.y = pk2(acc[mi][ni][8*t+2], acc[mi][ni][8*t+3]);
      dw.z = pk2(acc[mi][ni][8*t+4], acc[mi][ni][8*t+5]);
      dw.w = pk2(acc[mi][ni][8*t+6], acc[mi][ni][8*t+7]);
      B[kb][ni] = cast8(dw);
    }
  }
}

// B-frags of identity (PERM=0) or of the Pi permutation matrix (PERM=1)
template<int PERM>
__device__ __forceinline__ void ident_frags(b16x8 B[4][2], int lane){
  const int h = lane>>5, j0 = lane&31;
#pragma unroll
  for (int kt=0; kt<4; ++kt)
#pragma unroll
    for (int ni=0; ni<2; ++ni){
      const int col = j0 + 32*ni;
      int d[4];
#pragma unroll
      for (int dd=0; dd<4; ++dd){
        int r0 = 16*kt + 8*h + 2*dd, r1 = r0 + 1;
        int p0 = PERM ? perm64(r0) : r0;
        int p1 = PERM ? perm64(r1) : r1;
        d[dd] = (int)((p0==col ? 0x3F80u : 0u) | ((p1==col ? 0x3F80u : 0u) << 16));
      }
      int4 v; v.x=d[0]; v.y=d[1]; v.z=d[2]; v.w=d[3];
      B[kt][ni] = cast8(v);
    }
}

__device__ __forceinline__ float acc_wave_max(const f32x16 acc[2][2]){
  float m = 0.0f;
#pragma unroll
  for (int mi=0;mi<2;mi++)
#pragma unroll
    for (int ni=0;ni<2;ni++)
#pragma unroll
      for (int q=0;q<16;q++) m = fmaxf(m, acc[mi][ni][q]);
#pragma unroll
  for (int o=32;o>=1;o>>=1) m = fmaxf(m, __shfl_xor(m, o, 64));
  return m;
}

template<int PROW>
__device__ __forceinline__ void store_mat_lds(u16* mat, const f32x16 acc[2][2], float inv, int lane){
  const int h = lane>>5, j0 = lane&31;
#pragma unroll
  for (int mi=0;mi<2;mi++)
#pragma unroll
    for (int ni=0;ni<2;ni++)
#pragma unroll
      for (int r=0;r<16;r++){
        int gp = 32*mi + (r&3) + 8*(r>>2) + 4*h;
        int a = PROW ? perm64(gp) : gp;
        int b = perm64(32*ni + j0);
        mat[a*64 + (b ^ ((a&7)<<3))] = bfb(acc[mi][ni][r]*inv);
      }
}
template<int PROW>
__device__ __forceinline__ void store_mat_glob(u16* mat, const f32x16 acc[2][2], float inv, int lane){
  const int h = lane>>5, j0 = lane&31;
#pragma unroll
  for (int mi=0;mi<2;mi++)
#pragma unroll
    for (int ni=0;ni<2;ni++)
#pragma unroll
      for (int r=0;r<16;r++){
        int gp = 32*mi + (r&3) + 8*(r>>2) + 4*h;
        int a = PROW ? perm64(gp) : gp;
        int b = perm64(32*ni + j0);
        mat[a*64 + b] = bfb(acc[mi][ni][r]*inv);
      }
}
__device__ __forceinline__ void load_afrag_lds(const u16* mat, b16x8 A[2][4], int lane){
  const int h = lane>>5, i0 = lane&31;
#pragma unroll
  for (int mi=0;mi<2;mi++)
#pragma unroll
    for (int kt=0;kt<4;kt++){
      int i = 32*mi + i0;
      int cb = (16*kt + 8*h) ^ ((i&7)<<3);
      A[mi][kt] = cast8(*(const int4*)(mat + i*64 + cb));
    }
}
__device__ __forceinline__ void load_afrag_glob(const u16* mat, b16x8 A[2][4], int lane){
  const int h = lane>>5, i0 = lane&31;
#pragma unroll
  for (int mi=0;mi<2;mi++)
#pragma unroll
    for (int kt=0;kt<4;kt++){
      int i = 32*mi + i0;
      A[mi][kt] = cast8(*(const int4*)(mat + i*64 + 16*kt + 8*h));
    }
}

// ---------------- kernel 1: prep --------------------------------------------
// WpS: [16 chunks][64 rows][128 k] bf16, PRE-SWIZZLED within each row so that a
// linear global_load_lds copy of a chunk yields the XOR-swizzled LDS B-tile.
// E' = Pi*exp(T) padded 64x64.
__global__ void k_prep(const float* __restrict__ W, const float* __restrict__ T,
                       u16* __restrict__ WpS, u16* __restrict__ E){
  int tid = blockIdx.x*256 + threadIdx.x;
  int n = gridDim.x*256;
  for (int idx = tid; idx < 16*8192; idx += n){
    int kc = idx >> 13, e = idx & 8191;
    int r = e >> 7, m = e & 127;
    int kin = m ^ ((r&7)<<3);
    WpS[idx] = (r < KT) ? bfb(W[r*DM + kc*128 + kin]) : (u16)0;
  }
  for (int idx = tid; idx < 64*64; idx += n){
    int a = idx >> 6, b = idx & 63;
    int pa = perm64(a);
    E[idx] = (pa < KT && b < KT) ? bfb(__expf(T[pa*50 + b])) : (u16)0;
  }
}

// ---------------- kernel 2: emission GEMM (LDS-staged, coalesced) ------------
__device__ __forceinline__ void gll16(const void* g, void* l){
  __builtin_amdgcn_global_load_lds((const __attribute__((address_space(1))) u32*)g,
                                   (__attribute__((address_space(3))) u32*)l, 16, 0, 0);
}

__global__ __launch_bounds__(256, 2) void k_gemm(const float* __restrict__ in,
      const u16* __restrict__ WpS, const float* __restrict__ bias,
      const int* __restrict__ tags, float* __restrict__ feats, float* __restrict__ gout){
  __shared__ __align__(16) char smem[49152];
  u16* const bA = (u16*)smem;              // [2][4096] u16 (8 KB per buf), swizzled
  u16* const bB = (u16*)(smem + 16384);    // [2][8192] u16 (16 KB per buf), swizzled
  const int t = threadIdx.x;
  const int w = t>>6, lane = t&63;
  const int j0 = lane&31, h = lane>>5;
  const int wc = w&1, kh = w>>1;           // wc: output col half; kh: kt half
  const int row0 = blockIdx.x*32;

  const int aswz = (j0&7)<<3;              // u16-index XOR swizzle for frag reads
  float regA[2][8];
  f32x16 accE, accO;
#pragma unroll
  for (int q=0;q<16;q++){ accE[q]=0.f; accO[q]=0.f; }

  // A stage: 512 groups of 8 floats (32 rows x 16 col-groups), 2 per thread,
  // consecutive threads read consecutive 32 B within a row -> coalesced.
#define ISSUE_A(kc)                                                        \
  {                                                                        \
    _Pragma("unroll")                                                      \
    for (int i=0;i<2;i++){                                                 \
      int g = (i<<8) + t;                                                  \
      int r = g>>4, c8 = g&15;                                             \
      const float* p = in + (size_t)(row0 + r)*DM + (kc)*128 + c8*8;       \
      float4 f0 = *(const float4*)p;                                       \
      float4 f1 = *(const float4*)(p+4);                                   \
      regA[i][0]=f0.x; regA[i][1]=f0.y; regA[i][2]=f0.z; regA[i][3]=f0.w;  \
      regA[i][4]=f1.x; regA[i][5]=f1.y; regA[i][6]=f1.z; regA[i][7]=f1.w;  \
    }                                                                      \
  }
#define WRITE_A(d)                                                         \
  {                                                                        \
    _Pragma("unroll")                                                      \
    for (int i=0;i<2;i++){                                                 \
      int g = (i<<8) + t;                                                  \
      int r = g>>4, c8 = g&15;                                             \
      int4 dw; dw.x = pk2(regA[i][0],regA[i][1]); dw.y = pk2(regA[i][2],regA[i][3]); \
      dw.z = pk2(regA[i][4],regA[i][5]); dw.w = pk2(regA[i][6],regA[i][7]);\
      *(int4*)(bA + (d)*4096 + r*128 + ((c8*8) ^ ((r&7)<<3))) = dw;        \
    }                                                                      \
  }
#define ISSUE_B(kc, d)                                                     \
  {                                                                        \
    const u16* src = WpS + (kc)*8192 + w*2048 + lane*8;                    \
    u16* dst = bB + (d)*8192 + w*2048;                                     \
    _Pragma("unroll")                                                      \
    for (int i=0;i<4;i++) gll16(src + i*512, dst + i*512);                 \
  }

  // prologue: stage chunk 0 into buffers 0
  ISSUE_B(0, 0);
  ISSUE_A(0);
  WRITE_A(0);
  __syncthreads();

  for (int kc=0; kc<16; ++kc){
    const int d = kc & 1;
    if (kc < 15){ ISSUE_B(kc+1, d^1); ISSUE_A(kc+1); }
    const u16* Arow  = bA + d*4096 + j0*128;
    const u16* Brow  = bB + d*8192 + (32*wc + j0)*128;
#pragma unroll
    for (int kk=0; kk<2; ++kk){
      const int ktE = kh*4 + 2*kk, ktO = ktE + 1;
      b16x8 aE = cast8(*(const int4*)(Arow + ((ktE*16 + h*8) ^ aswz)));
      b16x8 bE = cast8(*(const int4*)(Brow + ((ktE*16 + h*8) ^ aswz)));
      accE = mfma_(aE, bE, accE);
      b16x8 aO = cast8(*(const int4*)(Arow + ((ktO*16 + h*8) ^ aswz)));
      b16x8 bO = cast8(*(const int4*)(Brow + ((ktO*16 + h*8) ^ aswz)));
      accO = mfma_(aO, bO, accO);
    }
    if (kc < 15) WRITE_A(d^1);
    __syncthreads();
  }

  // epilogue: reduce kt-halves via LDS (aliases stage buffers; loop ended with barrier)
  f32x16 accS;
#pragma unroll
  for (int q=0;q<16;q++) accS[q] = accE[q] + accO[q];
  float* planes = (float*)smem;            // [2][32][64]
  float* tile   = (float*)(smem + 16384);  // [32][66]
  float* mrow   = (float*)(smem + 24832);  // [32]
#pragma unroll
  for (int r=0;r<16;r++){
    int gp = (r&3) + 8*(r>>2) + 4*h;
    planes[(kh*32 + gp)*64 + 32*wc + j0] = accS[r];
  }
  __syncthreads();
  for (int cidx = t; cidx < 2048; cidx += 256){
    int g = cidx>>6, c = cidx&63;
    float v = planes[g*64+c] + planes[(32+g)*64+c];
    tile[g*66+c] = (c<KT) ? (v + bias[c]) : -1e4f;
  }
  __syncthreads();
  if (t < 32){
    int g = t;
    float mx = -1e30f;
    for (int c=0;c<KT;c++) mx = fmaxf(mx, tile[g*66+c]);
    mrow[g] = mx;
    int tt = row0 + g;
    gout[tt] = tile[g*66 + tags[tt]] - mx;
  }
  __syncthreads();
  for (int cidx = t; cidx < 2048; cidx += 256){
    int g = cidx>>6, c = cidx&63;
    feats[(size_t)(row0+g)*64 + c] = (c<KT) ? (tile[g*66+c] - mrow[g]) : -1e4f;
  }
#undef ISSUE_A
#undef WRITE_A
#undef ISSUE_B
}

// ---------------- kernel 3: chunked scan (8 steps/wave) + in-block 8->1 ------
__global__ __launch_bounds__(512, 2) void k_scan(const float* __restrict__ feats,
        const u16* __restrict__ Emat, u16* __restrict__ M1, float* __restrict__ S1){
  const int w = threadIdx.x >> 6, lane = threadIdx.x & 63;
  const int h = lane>>5;
  const int blk = blockIdx.x;
  const int t0 = (blk*8 + w)*8;
  __shared__ __align__(16) float u_lds[8][64];
  __shared__ __align__(16) u16 mats[8][4096];
  __shared__ float logs[8];

  b16x8 Af[2][4];
  load_afrag_glob(Emat, Af, lane);
  b16x8 Bf[4][2];
  ident_frags<0>(Bf, lane);
  const int pl = perm64(lane);
  float x = feats[(size_t)t0*64 + pl];
  f32x16 acc[2][2];
#pragma unroll
  for (int s=0;s<8;s++){
    u_lds[w][lane] = __expf(x);
    if (s<7) x = feats[(size_t)(t0+s+1)*64 + pl];
    mm64(Af, Bf, acc);
    float uu0[16], uu1[16];
#pragma unroll
    for (int k2=0;k2<4;k2++){
      float4 v0 = *(const float4*)&u_lds[w][      8*k2 + 4*h];
      float4 v1 = *(const float4*)&u_lds[w][32 +  8*k2 + 4*h];
      uu0[4*k2+0]=v0.x; uu0[4*k2+1]=v0.y; uu0[4*k2+2]=v0.z; uu0[4*k2+3]=v0.w;
      uu1[4*k2+0]=v1.x; uu1[4*k2+1]=v1.y; uu1[4*k2+2]=v1.z; uu1[4*k2+3]=v1.w;
    }
#pragma unroll
    for (int ni=0;ni<2;ni++)
#pragma unroll
      for (int r=0;r<16;r++){
        acc[0][ni][r] *= uu0[r];
        acc[1][ni][r] *= uu1[r];
      }
    repack(acc, Bf);
  }
  float m = acc_wave_max(acc);
  float inv = 1.0f/m;
  store_mat_lds<1>(mats[w], acc, inv, lane);
  if (lane==0) logs[w] = __logf(m);
  __syncthreads();
  if (w==0){
    float slog = logs[0]+logs[1]+logs[2]+logs[3]+logs[4]+logs[5]+logs[6]+logs[7];
    b16x8 Bc[4][2]; ident_frags<1>(Bc, lane);
    f32x16 a2[2][2];
#pragma unroll 1
    for (int m8=0;m8<8;m8++){
      b16x8 Am[2][4];
      load_afrag_lds(mats[m8], Am, lane);
      mm64(Am, Bc, a2);
      repack(a2, Bc);
    }
    float m2 = acc_wave_max(a2);
    slog += __logf(m2);
    store_mat_glob<0>(M1 + (size_t)blk*4096, a2, 1.0f/m2, lane);
    if (lane==0) S1[blk] = slog;
  }
}

// ---------------- kernel 4: combine 8 matrices -> 1 (256 -> 32) --------------
__global__ __launch_bounds__(64) void k_comb8(const u16* __restrict__ Min, const float* __restrict__ Sin,
      u16* __restrict__ Mout, float* __restrict__ Sout){
  const int lane = threadIdx.x & 63;
  const int blk = blockIdx.x;
  b16x8 Bc[4][2]; ident_frags<1>(Bc, lane);
  f32x16 a2[2][2];
  float slog = 0.f;
#pragma unroll 1
  for (int m=0;m<8;m++){
    b16x8 Am[2][4];
    load_afrag_glob(Min + (size_t)(blk*8+m)*4096, Am, lane);
    slog += Sin[blk*8+m];
    mm64(Am, Bc, a2);
    repack(a2, Bc);
  }
  float mx = acc_wave_max(a2);
  slog += __logf(mx);
  store_mat_glob<0>(Mout + (size_t)blk*4096, a2, 1.0f/mx, lane);
  if (lane==0) Sout[blk] = slog;
}

// ---------------- kernel 5: final 32 -> 1, LSE, gold, output -----------------
__global__ __launch_bounds__(512, 2) void k_final(const u16* __restrict__ M2, const float* __restrict__ S2,
      const float* __restrict__ T, const int* __restrict__ tags,
      const float* __restrict__ gvec, float* __restrict__ out){
  const int w = threadIdx.x>>6, lane = threadIdx.x&63;
  __shared__ __align__(16) u16 mats[8][4096];
  __shared__ float logs[8];
  __shared__ float alpha[64];
  __shared__ float red[512];
  __shared__ float slog_sh;
  {
    b16x8 Bc[4][2]; ident_frags<1>(Bc, lane);
    f32x16 a2[2][2];
    float sl = 0.f;
#pragma unroll 1
    for (int m=0;m<4;m++){
      b16x8 Am[2][4];
      load_afrag_glob(M2 + (size_t)(w*4+m)*4096, Am, lane);
      sl += S2[w*4+m];
      mm64(Am, Bc, a2);
      repack(a2, Bc);
    }
    float mx = acc_wave_max(a2);
    sl += __logf(mx);
    store_mat_lds<0>(mats[w], a2, 1.0f/mx, lane);
    if (lane==0) logs[w] = sl;
  }
  __syncthreads();
  if (w==0){
    b16x8 Bc[4][2]; ident_frags<1>(Bc, lane);
    f32x16 a2[2][2];
#pragma unroll 1
    for (int m=0;m<8;m++){
      b16x8 Am[2][4];
      load_afrag_lds(mats[m], Am, lane);
      mm64(Am, Bc, a2);
      repack(a2, Bc);
    }
    float sl = logs[0]+logs[1]+logs[2]+logs[3]+logs[4]+logs[5]+logs[6]+logs[7];
    if ((lane&31)==16){   // column START=48 lives in lanes 16 / 48 (ni=1)
      const int h = lane>>5;
#pragma unroll
      for (int mi=0;mi<2;mi++)
#pragma unroll
        for (int r=0;r<16;r++){
          int gp = 32*mi + (r&3) + 8*(r>>2) + 4*h;
          alpha[gp] = a2[mi][1][r];
        }
    }
    if (lane==0) slog_sh = sl;
  }
  // gold score (deterministic tree reduction)
  float part = 0.f;
  for (int t = threadIdx.x; t < SEQ; t += 512) part += gvec[t];
  for (int idx = threadIdx.x; idx < SEQ+1; idx += 512){
    int s0 = (idx==0) ? NST : tags[idx-1];
    int s1 = (idx<SEQ) ? tags[idx] : NSP;
    part += T[s1*50 + s0];
  }
  red[threadIdx.x] = part;
  for (int st=256; st>0; st>>=1){
    __syncthreads();
    if (threadIdx.x < st) red[threadIdx.x] += red[threadIdx.x + st];
  }
  __syncthreads();
  if (threadIdx.x < 64){
    float a = alpha[lane];
    float term = (lane < KT && a > 0.f) ? (__logf(a) + slog_sh + T[NSP*50 + lane]) : -1e30f;
    float tm = term;
#pragma unroll
    for (int o=32;o>=1;o>>=1) tm = fmaxf(tm, __shfl_xor(tm, o, 64));
    float e = __expf(term - tm);
#pragma unroll
    for (int o=32;o>=1;o>>=1) e += __shfl_xor(e, o, 64);
    if (threadIdx.x == 0) out[0] = (tm + __logf(e)) - red[0];
  }
}

extern "C" void kernel_launch(void* const* d_in, const int* in_sizes, int n_in,
                              void* d_out, int out_size, void* d_ws, size_t ws_size,
                              hipStream_t stream) {
  (void)in_sizes; (void)n_in; (void)out_size; (void)ws_size;
  const float* input = (const float*)d_in[0];
  const int*   tags  = (const int*)  d_in[1];
  const float* W     = (const float*)d_in[2];
  const float* bias  = (const float*)d_in[3];
  const float* T     = (const float*)d_in[4];

  char* ws = (char*)d_ws;
  float* feats = (float*)(ws + 0);          // 16384*64*4  = 4194304
  float* gvec  = (float*)(ws + 4194304);    // 16384*4     = 65536
  u16*   WpS   = (u16*)  (ws + 4259840);    // 16*8192*2   = 262144 (chunked, pre-swizzled)
  u16*   Emat  = (u16*)  (ws + 4521984);    // 64*64*2     = 8192
  u16*   M1    = (u16*)  (ws + 4530176);    // 256*4096*2  = 2097152
  float* S1    = (float*)(ws + 6627328);    // 256*4 -> pad 1024
  u16*   M2    = (u16*)  (ws + 6628352);    // 32*4096*2   = 262144
  float* S2    = (float*)(ws + 6890496);    // 32*4

  k_prep <<<256, 256, 0, stream>>>(W, T, WpS, Emat);
  k_gemm <<<512, 256, 0, stream>>>(input, WpS, bias, tags, feats, gvec);
  k_scan <<<256, 512, 0, stream>>>(feats, Emat, M1, S1);
  k_comb8<<<32,  64,  0, stream>>>(M1, S1, M2, S2);
  k_final<<<1,   512, 0, stream>>>(M2, S2, T, tags, gvec, (float*)d_out);
}

// Round 3
// 97.666 us; speedup vs baseline: 1.1811x; 1.1811x over previous
//
#include <hip/hip_runtime.h>

typedef unsigned short u16;
typedef unsigned int u32;
typedef __bf16 b16x8 __attribute__((ext_vector_type(8)));
typedef float f32x16 __attribute__((ext_vector_type(16)));

#define SEQ   16384
#define DM    2048
#define KT    50
#define NST   48
#define NSP   49

// involution: swap rows 4-7 <-> 8-11 within each 16-block
__device__ __forceinline__ int perm64(int g){
  int q = (g>>2)&3;
  return (q==1 || q==2) ? (g^12) : g;
}
__device__ __forceinline__ u16 bfb(float f){
  __bf16 b = (__bf16)f;
  return __builtin_bit_cast(u16, b);
}
__device__ __forceinline__ int pk2(float a, float b){
  return (int)((u32)bfb(a) | ((u32)bfb(b) << 16));
}
__device__ __forceinline__ b16x8 cast8(int4 v){ return __builtin_bit_cast(b16x8, v); }

__device__ __forceinline__ f32x16 mfma_(b16x8 a, b16x8 b, f32x16 c){
  return __builtin_amdgcn_mfma_f32_32x32x16_bf16(a, b, c, 0, 0, 0);
}

// acc = A * B   (64x64x64, A-frags [mi][kt], B-frags [kt][ni])
__device__ __forceinline__ void mm64(const b16x8 A[2][4], const b16x8 B[4][2], f32x16 acc[2][2]){
#pragma unroll
  for (int mi=0; mi<2; ++mi)
#pragma unroll
    for (int ni=0; ni<2; ++ni){
      f32x16 a;
#pragma unroll
      for (int q=0;q<16;q++) a[q] = 0.0f;
#pragma unroll
      for (int kt=0; kt<4; ++kt) a = mfma_(A[mi][kt], B[kt][ni], a);
      acc[mi][ni] = a;
    }
}

// acc (C/D layout) -> B-frags of the next matmul (B_phys = Pi * ACC, in-lane).
__device__ __forceinline__ void repack(const f32x16 acc[2][2], b16x8 B[4][2]){
#pragma unroll
  for (int kb=0; kb<4; ++kb){
    const int mi = kb>>1, t = kb&1;
#pragma unroll
    for (int ni=0; ni<2; ++ni){
      int4 dw;
      dw.x = pk2(acc[mi][ni][8*t+0], acc[mi][ni][8*t+1]);
      dw.y = pk2(acc[mi][ni][8*t+2], acc[mi][ni][8*t+3]);
      dw.z = pk2(acc[mi][ni][8*t+4], acc[mi][ni][8*t+5]);
      dw.w = pk2(acc[mi][ni][8*t+6], acc[mi][ni][8*t+7]);
      B[kb][ni] = cast8(dw);
    }
  }
}
__device__ __forceinline__ void repack_s(const f32x16 acc[2][2], b16x8 B[4][2], float s){
#pragma unroll
  for (int kb=0; kb<4; ++kb){
    const int mi = kb>>1, t = kb&1;
#pragma unroll
    for (int ni=0; ni<2; ++ni){
      int4 dw;
      dw.x = pk2(acc[mi][ni][8*t+0]*s, acc[mi][ni][8*t+1]*s);
      dw.y = pk2(acc[mi][ni][8*t+2]*s, acc[mi][ni][8*t+3]*s);
      dw.z = pk2(acc[mi][ni][8*t+4]*s, acc[mi][ni][8*t+5]*s);
      dw.w = pk2(acc[mi][ni][8*t+6]*s, acc[mi][ni][8*t+7]*s);
      B[kb][ni] = cast8(dw);
    }
  }
}

// B-frags of identity (PERM=0) or of the Pi permutation matrix (PERM=1)
template<int PERM>
__device__ __forceinline__ void ident_frags(b16x8 B[4][2], int lane){
  const int h = lane>>5, j0 = lane&31;
#pragma unroll
  for (int kt=0; kt<4; ++kt)
#pragma unroll
    for (int ni=0; ni<2; ++ni){
      const int col = j0 + 32*ni;
      int d[4];
#pragma unroll
      for (int dd=0; dd<4; ++dd){
        int r0 = 16*kt + 8*h + 2*dd, r1 = r0 + 1;
        int p0 = PERM ? perm64(r0) : r0;
        int p1 = PERM ? perm64(r1) : r1;
        d[dd] = (int)((p0==col ? 0x3F80u : 0u) | ((p1==col ? 0x3F80u : 0u) << 16));
      }
      int4 v; v.x=d[0]; v.y=d[1]; v.z=d[2]; v.w=d[3];
      B[kt][ni] = cast8(v);
    }
}

__device__ __forceinline__ float acc_wave_max(const f32x16 acc[2][2]){
  float m = 0.0f;
#pragma unroll
  for (int mi=0;mi<2;mi++)
#pragma unroll
    for (int ni=0;ni<2;ni++)
#pragma unroll
      for (int q=0;q<16;q++) m = fmaxf(m, acc[mi][ni][q]);
#pragma unroll
  for (int o=32;o>=1;o>>=1) m = fmaxf(m, __shfl_xor(m, o, 64));
  return m;
}

template<int PROW>
__device__ __forceinline__ void store_mat_lds(u16* mat, const f32x16 acc[2][2], float inv, int lane){
  const int h = lane>>5, j0 = lane&31;
#pragma unroll
  for (int mi=0;mi<2;mi++)
#pragma unroll
    for (int ni=0;ni<2;ni++)
#pragma unroll
      for (int r=0;r<16;r++){
        int gp = 32*mi + (r&3) + 8*(r>>2) + 4*h;
        int a = PROW ? perm64(gp) : gp;
        int b = perm64(32*ni + j0);
        mat[a*64 + (b ^ ((a&7)<<3))] = bfb(acc[mi][ni][r]*inv);
      }
}
template<int PROW>
__device__ __forceinline__ void store_mat_glob(u16* mat, const f32x16 acc[2][2], float inv, int lane){
  const int h = lane>>5, j0 = lane&31;
#pragma unroll
  for (int mi=0;mi<2;mi++)
#pragma unroll
    for (int ni=0;ni<2;ni++)
#pragma unroll
      for (int r=0;r<16;r++){
        int gp = 32*mi + (r&3) + 8*(r>>2) + 4*h;
        int a = PROW ? perm64(gp) : gp;
        int b = perm64(32*ni + j0);
        mat[a*64 + b] = bfb(acc[mi][ni][r]*inv);
      }
}
__device__ __forceinline__ void load_afrag_lds(const u16* mat, b16x8 A[2][4], int lane){
  const int h = lane>>5, i0 = lane&31;
#pragma unroll
  for (int mi=0;mi<2;mi++)
#pragma unroll
    for (int kt=0;kt<4;kt++){
      int i = 32*mi + i0;
      int cb = (16*kt + 8*h) ^ ((i&7)<<3);
      A[mi][kt] = cast8(*(const int4*)(mat + i*64 + cb));
    }
}
__device__ __forceinline__ void load_afrag_glob(const u16* mat, b16x8 A[2][4], int lane){
  const int h = lane>>5, i0 = lane&31;
#pragma unroll
  for (int mi=0;mi<2;mi++)
#pragma unroll
    for (int kt=0;kt<4;kt++){
      int i = 32*mi + i0;
      A[mi][kt] = cast8(*(const int4*)(mat + i*64 + 16*kt + 8*h));
    }
}

// ============ kernel 1: emission GEMM from raw inputs + gold partials ========
// 256 blocks x 512 thr, 64 seq rows/block, BK=128, double-buffered LDS,
// B (=W) converted fp32->bf16 inline (W is L2-resident across blocks).
__global__ __launch_bounds__(512, 2) void k_gemm(const float* __restrict__ in,
      const int* __restrict__ tags, const float* __restrict__ W,
      const float* __restrict__ bias, const float* __restrict__ T,
      float* __restrict__ feats, float* __restrict__ gpart, int* __restrict__ counter){
  __shared__ __align__(16) char smem[65536];
  u16* const bA = (u16*)smem;              // [2][64*128] swizzled
  u16* const bB = (u16*)(smem + 32768);    // [2][64*128] swizzled
  const int t = threadIdx.x;
  const int w = t>>6, lane = t&63;
  const int j0 = lane&31, h = lane>>5;
  const int rh = w&1, ch = (w>>1)&1, kq = (w>>2)&1;
  const int row0 = blockIdx.x*64;
  const int aswz = (j0&7)<<3;
  if (blockIdx.x==0 && t==0) *counter = 0;

  float rA[2][8], rB[2][8];
  f32x16 acc;
#pragma unroll
  for (int q=0;q<16;q++) acc[q]=0.f;

#define LOADCHUNK(kc)                                                       \
  { _Pragma("unroll")                                                       \
    for (int i=0;i<2;i++){                                                  \
      int g=(i<<9)+t; int r=g>>4, c8=g&15;                                  \
      const float* p = in + (size_t)(row0+r)*DM + (kc)*128 + c8*8;          \
      float4 f0=*(const float4*)p, f1=*(const float4*)(p+4);                \
      rA[i][0]=f0.x; rA[i][1]=f0.y; rA[i][2]=f0.z; rA[i][3]=f0.w;           \
      rA[i][4]=f1.x; rA[i][5]=f1.y; rA[i][6]=f1.z; rA[i][7]=f1.w;           \
      if (r < KT){                                                          \
        const float* q2 = W + (size_t)r*DM + (kc)*128 + c8*8;               \
        float4 g0=*(const float4*)q2, g1=*(const float4*)(q2+4);            \
        rB[i][0]=g0.x; rB[i][1]=g0.y; rB[i][2]=g0.z; rB[i][3]=g0.w;         \
        rB[i][4]=g1.x; rB[i][5]=g1.y; rB[i][6]=g1.z; rB[i][7]=g1.w;         \
      } else {                                                              \
        _Pragma("unroll") for (int z=0;z<8;z++) rB[i][z]=0.f;               \
      }                                                                     \
    } }
#define WRITECHUNK(d)                                                       \
  { _Pragma("unroll")                                                       \
    for (int i=0;i<2;i++){                                                  \
      int g=(i<<9)+t; int r=g>>4, c8=g&15;                                  \
      int off = r*128 + ((c8*8) ^ ((r&7)<<3));                              \
      int4 da; da.x=pk2(rA[i][0],rA[i][1]); da.y=pk2(rA[i][2],rA[i][3]);    \
      da.z=pk2(rA[i][4],rA[i][5]); da.w=pk2(rA[i][6],rA[i][7]);             \
      *(int4*)(bA + (d)*8192 + off) = da;                                   \
      int4 db; db.x=pk2(rB[i][0],rB[i][1]); db.y=pk2(rB[i][2],rB[i][3]);    \
      db.z=pk2(rB[i][4],rB[i][5]); db.w=pk2(rB[i][6],rB[i][7]);             \
      *(int4*)(bB + (d)*8192 + off) = db;                                   \
    } }

  LOADCHUNK(0); WRITECHUNK(0);
  __syncthreads();
  for (int kc=0; kc<16; ++kc){
    const int d = kc & 1;
    if (kc < 15) LOADCHUNK(kc+1);
    const u16* Arow = bA + d*8192 + (32*rh + j0)*128;
    const u16* Brow = bB + d*8192 + (32*ch + j0)*128;
#pragma unroll
    for (int kk=0;kk<4;kk++){
      const int kt = kq*4 + kk;
      b16x8 aF = cast8(*(const int4*)(Arow + ((kt*16 + h*8) ^ aswz)));
      b16x8 bF = cast8(*(const int4*)(Brow + ((kt*16 + h*8) ^ aswz)));
      acc = mfma_(aF, bF, acc);
    }
    if (kc < 15) WRITECHUNK(d^1);
    __syncthreads();
  }
#undef LOADCHUNK
#undef WRITECHUNK

  // epilogue (LDS reuse is safe: loop ended with a barrier)
  float* planes = (float*)smem;            // [2][64][64]
  float* tile   = (float*)(smem + 32768);  // [64][66]
  float* mrow   = (float*)(smem + 49664);  // [64]
#pragma unroll
  for (int r=0;r<16;r++){
    int gp = (r&3) + 8*(r>>2) + 4*h;
    planes[kq*4096 + (32*rh + gp)*64 + 32*ch + j0] = acc[r];
  }
  __syncthreads();
  for (int cidx = t; cidx < 4096; cidx += 512){
    int g = cidx>>6, c = cidx&63;
    float v = planes[cidx] + planes[4096 + cidx];
    tile[g*66+c] = (c<KT) ? (v + bias[c]) : -1e4f;
  }
  __syncthreads();
  if (t < 64){
    int g = t;
    float mx = -1e30f;
    for (int c=0;c<KT;c++) mx = fmaxf(mx, tile[g*66+c]);
    mrow[g] = mx;
    int tt = row0 + g;
    int s1 = tags[tt];
    int s0 = (tt==0) ? NST : tags[tt-1];
    float part = (tile[g*66 + s1] - mx) + T[s1*50 + s0];
    if (tt == SEQ-1) part += T[NSP*50 + s1];
#pragma unroll
    for (int o=32;o>=1;o>>=1) part += __shfl_xor(part, o, 64);
    if (t==0) gpart[blockIdx.x] = part;
  }
  __syncthreads();
  for (int cidx = t; cidx < 4096; cidx += 512){
    int g = cidx>>6, c = cidx&63;
    feats[(size_t)(row0+g)*64 + c] = (c<KT) ? (tile[g*66+c] - mrow[g]) : -1e4f;
  }
}

// ============ kernel 2: scan (16 steps/wave) + tree + last-block finale ======
__global__ __launch_bounds__(512, 2) void k_scan(const float* __restrict__ feats,
        const float* __restrict__ T, const float* __restrict__ gpart,
        int* __restrict__ counter, u16* __restrict__ M1, float* __restrict__ S1,
        float* __restrict__ out){
  const int t = threadIdx.x;
  const int w = t>>6, lane = t&63;
  const int h = lane>>5;
  const int blk = blockIdx.x;
  __shared__ __align__(16) u16 E_lds[4096];
  __shared__ __align__(16) float u_lds[8][64];
  __shared__ __align__(16) u16 mats[8][4096];
  __shared__ float logs[8];
  __shared__ float alpha[64];
  __shared__ int bcast;

  // build E' = Pi*exp(T) swizzled in LDS
  for (int idx = t; idx < 4096; idx += 512){
    int a = idx>>6, b = idx&63;
    int pa = perm64(a);
    float v = (pa<KT && b<KT) ? __expf(T[pa*50 + b]) : 0.f;
    E_lds[a*64 + (b ^ ((a&7)<<3))] = bfb(v);
  }
  __syncthreads();

  b16x8 Af[2][4];
  load_afrag_lds(E_lds, Af, lane);
  b16x8 Bf[4][2];
  ident_frags<0>(Bf, lane);
  const int pl = perm64(lane);
  const int t0 = (blk*8 + w)*16;
  float x = feats[(size_t)t0*64 + pl];
  f32x16 acc[2][2];
#pragma unroll
  for (int s=0;s<16;s++){
    u_lds[w][lane] = __expf(x);
    if (s<15) x = feats[(size_t)(t0+s+1)*64 + pl];
    mm64(Af, Bf, acc);
    float uu0[16], uu1[16];
#pragma unroll
    for (int k2=0;k2<4;k2++){
      float4 v0 = *(const float4*)&u_lds[w][      8*k2 + 4*h];
      float4 v1 = *(const float4*)&u_lds[w][32 +  8*k2 + 4*h];
      uu0[4*k2+0]=v0.x; uu0[4*k2+1]=v0.y; uu0[4*k2+2]=v0.z; uu0[4*k2+3]=v0.w;
      uu1[4*k2+0]=v1.x; uu1[4*k2+1]=v1.y; uu1[4*k2+2]=v1.z; uu1[4*k2+3]=v1.w;
    }
#pragma unroll
    for (int ni=0;ni<2;ni++)
#pragma unroll
      for (int r=0;r<16;r++){
        acc[0][ni][r] *= uu0[r];
        acc[1][ni][r] *= uu1[r];
      }
    repack(acc, Bf);
  }
  float m = acc_wave_max(acc);
  store_mat_lds<1>(mats[w], acc, 1.0f/m, lane);
  if (lane==0) logs[w] = __logf(m);
  __syncthreads();
  if (w==0){
    float slog = logs[0]+logs[1]+logs[2]+logs[3]+logs[4]+logs[5]+logs[6]+logs[7];
    b16x8 Bc[4][2]; ident_frags<1>(Bc, lane);
    f32x16 a2[2][2];
#pragma unroll 1
    for (int m8=0;m8<8;m8++){
      b16x8 Am[2][4];
      load_afrag_lds(mats[m8], Am, lane);
      mm64(Am, Bc, a2);
      repack(a2, Bc);
    }
    float m2 = acc_wave_max(a2);
    slog += __logf(m2);
    store_mat_glob<0>(M1 + (size_t)blk*4096, a2, 1.0f/m2, lane);
    if (lane==0) S1[blk] = slog;
  }
  __syncthreads();
  if (t==0){
    __threadfence();                       // release M1/S1 to device scope
    bcast = atomicAdd(counter, 1);
  }
  __syncthreads();
  if (bcast != gridDim.x - 1) return;      // only the LAST block continues
  __threadfence();                         // acquire: invalidate stale caches

  // ---- stage 1: 8 waves x 16 mats each (prefetched chain, renorm at mid) ----
  {
    b16x8 Bc[4][2]; ident_frags<1>(Bc, lane);
    f32x16 a2[2][2];
    float sl = 0.f;
    b16x8 Acur[2][4], Anx[2][4];
    load_afrag_glob(M1 + (size_t)(w*16)*4096, Acur, lane);
#pragma unroll 1
    for (int mm=0; mm<16; mm++){
      if (mm<15) load_afrag_glob(M1 + (size_t)(w*16+mm+1)*4096, Anx, lane);
      sl += S1[w*16+mm];
      mm64(Acur, Bc, a2);
      if (mm==7){
        float mx = acc_wave_max(a2);
        sl += __logf(mx);
        repack_s(a2, Bc, 1.0f/mx);
      } else {
        repack(a2, Bc);
      }
#pragma unroll
      for (int mi=0;mi<2;mi++)
#pragma unroll
        for (int kt=0;kt<4;kt++) Acur[mi][kt] = Anx[mi][kt];
    }
    float mx = acc_wave_max(a2);
    sl += __logf(mx);
    store_mat_lds<0>(mats[w], a2, 1.0f/mx, lane);
    if (lane==0) logs[w] = sl;
  }
  __syncthreads();
  // ---- stage 2: wave 0 combines 8, extracts alpha, LSE, gold, output -------
  if (w==0){
    b16x8 Bc[4][2]; ident_frags<1>(Bc, lane);
    f32x16 a2[2][2];
#pragma unroll 1
    for (int m8=0;m8<8;m8++){
      b16x8 Am[2][4];
      load_afrag_lds(mats[m8], Am, lane);
      mm64(Am, Bc, a2);
      repack(a2, Bc);
    }
    float slog = logs[0]+logs[1]+logs[2]+logs[3]+logs[4]+logs[5]+logs[6]+logs[7];
    if ((lane&31)==16){   // column START=48 lives in lanes 16 / 48 (ni=1)
#pragma unroll
      for (int mi=0;mi<2;mi++)
#pragma unroll
        for (int r=0;r<16;r++){
          int gp = 32*mi + (r&3) + 8*(r>>2) + 4*h;
          alpha[gp] = a2[mi][1][r];
        }
    }
    float gold = gpart[lane] + gpart[lane+64] + gpart[lane+128] + gpart[lane+192];
#pragma unroll
    for (int o=32;o>=1;o>>=1) gold += __shfl_xor(gold, o, 64);
    float a = alpha[lane];
    float term = (lane < KT && a > 0.f) ? (__logf(a) + slog + T[NSP*50 + lane]) : -1e30f;
    float tm = term;
#pragma unroll
    for (int o=32;o>=1;o>>=1) tm = fmaxf(tm, __shfl_xor(tm, o, 64));
    float e = __expf(term - tm);
#pragma unroll
    for (int o=32;o>=1;o>>=1) e += __shfl_xor(e, o, 64);
    if (lane==0) out[0] = (tm + __logf(e)) - gold;
  }
}

extern "C" void kernel_launch(void* const* d_in, const int* in_sizes, int n_in,
                              void* d_out, int out_size, void* d_ws, size_t ws_size,
                              hipStream_t stream) {
  (void)in_sizes; (void)n_in; (void)out_size; (void)ws_size;
  const float* input = (const float*)d_in[0];
  const int*   tags  = (const int*)  d_in[1];
  const float* W     = (const float*)d_in[2];
  const float* bias  = (const float*)d_in[3];
  const float* T     = (const float*)d_in[4];

  char* ws = (char*)d_ws;
  float* feats   = (float*)(ws + 0);        // 16384*64*4 = 4194304
  float* gpart   = (float*)(ws + 4194304);  // 256*4      = 1024
  int*   counter = (int*)  (ws + 4195328);  // 4 (re-zeroed by k_gemm each call)
  u16*   M1      = (u16*)  (ws + 4195840);  // 128*4096*2 = 1048576
  float* S1      = (float*)(ws + 5244416);  // 128*4

  k_gemm<<<256, 512, 0, stream>>>(input, tags, W, bias, T, feats, gpart, counter);
  k_scan<<<128, 512, 0, stream>>>(feats, T, gpart, counter, M1, S1, (float*)d_out);
}